// Round 2
// baseline (283.089 us; speedup 1.0000x reference)
//
#include <hip/hip_runtime.h>

#define BB 1024
#define TT 1024
#define KQ 15
#define KT 20
#define NDOF 7
#define CHK 256              // t's per chunk == blockDim
#define NCHK (TT / CHK)
#define KTP 21               // padded t-basis stride (odd -> conflict-free)

// Output layout (flat float offsets, in reference return order)
#define OFF_MODEL 0
#define OFF_QDL   1
#define OFF_QDDL  (1 + BB*NDOF)
#define OFF_QDDDL (1 + 2*BB*NDOF)
#define OFF_TQL   (1 + 3*BB*NDOF)
#define OFF_Q     (1 + 4*BB*NDOF)
#define OFF_QD    (OFF_Q    + (size_t)BB*TT*NDOF)
#define OFF_QDD   (OFF_QD   + (size_t)BB*TT*NDOF)
#define OFF_QDDD  (OFF_QDD  + (size_t)BB*TT*NDOF)
#define OFF_TQ    (OFF_QDDD + (size_t)BB*TT*NDOF)
#define OFF_T     (OFF_TQ   + (size_t)BB*TT*NDOF)
#define OFF_TCUM  (OFF_T    + (size_t)BB)
#define OFF_DT    (OFF_TCUM + (size_t)BB*TT)

// LDS sub-offsets inside sbuf (floats)
#define QB_STR    (CHK*KQ)          // 3840 per q-basis array
#define TB_STR    (CHK*KTP)         // 5376 per t-basis array
#define OS_STR    (CHK*NDOF)        // 1792 per output array
#define SBUF_FL   (3*TB_STR)        // 16128 floats = 64512 B (max of phases)

__device__ __forceinline__ float hub(float v, float lim) {
    // huber(relu(|v| - lim)), delta = 1.0
    float x = fabsf(v) - lim;
    x = fmaxf(x, 0.0f);
    return (x < 1.0f) ? 0.5f * x * x : (x - 0.5f);
}

__global__ __launch_bounds__(256) void feas_main(
    const float* __restrict__ q_cps, const float* __restrict__ t_cps,
    const float* __restrict__ Nb,  const float* __restrict__ dNb,
    const float* __restrict__ ddNb, const float* __restrict__ dddNb,
    const float* __restrict__ Ntb, const float* __restrict__ dNtb,
    const float* __restrict__ ddNtb,
    const float* __restrict__ qd_lim, const float* __restrict__ qdd_lim,
    const float* __restrict__ qddd_lim,
    float* __restrict__ out)
{
    const int b   = blockIdx.x;
    const int tid = threadIdx.x;

    __shared__ float sbuf[SBUF_FL];   // 63 KB, phase-reused

    // wave-uniform pointers -> compiler emits scalar s_load (no LDS broadcast needed)
    const float* cps = q_cps + (size_t)b * KQ * NDOF;
    const float* tcp = t_cps + (size_t)b * KT;

    float lqd[NDOF], lqdd[NDOF], lqddd[NDOF];
    #pragma unroll
    for (int d = 0; d < NDOF; d++) { lqd[d] = 0.f; lqdd[d] = 0.f; lqddd[d] = 0.f; }

    #pragma unroll 1
    for (int c = 0; c < NCHK; ++c) {
        // ---- A1: stage q-basis chunk (4 arrays x 3840 floats) coalesced float4 ----
        {
            const float4* s0 = (const float4*)(Nb    + (size_t)c * QB_STR);
            const float4* s1 = (const float4*)(dNb   + (size_t)c * QB_STR);
            const float4* s2 = (const float4*)(ddNb  + (size_t)c * QB_STR);
            const float4* s3 = (const float4*)(dddNb + (size_t)c * QB_STR);
            float4* dst = (float4*)sbuf;
            #pragma unroll
            for (int j = 0; j < 4; ++j) {
                const int idx = j * 256 + tid;
                if (idx < QB_STR / 4) {
                    dst[0 * (QB_STR/4) + idx] = s0[idx];
                    dst[1 * (QB_STR/4) + idx] = s1[idx];
                    dst[2 * (QB_STR/4) + idx] = s2[idx];
                    dst[3 * (QB_STR/4) + idx] = s3[idx];
                }
            }
        }
        __syncthreads();

        // ---- B1: q-spline sums from LDS (stride 15, conflict-free) ----
        float aq[NDOF], a1[NDOF], a2[NDOF], a3[NDOF];
        #pragma unroll
        for (int d = 0; d < NDOF; d++) { aq[d] = 0.f; a1[d] = 0.f; a2[d] = 0.f; a3[d] = 0.f; }
        {
            const float* p = sbuf + tid * KQ;
            #pragma unroll
            for (int k = 0; k < KQ; ++k) {
                const float n0 = p[k];
                const float n1 = p[1 * QB_STR + k];
                const float n2 = p[2 * QB_STR + k];
                const float n3 = p[3 * QB_STR + k];
                #pragma unroll
                for (int d = 0; d < NDOF; ++d) {
                    const float cc = cps[k * NDOF + d];
                    aq[d] = fmaf(n0, cc, aq[d]);
                    a1[d] = fmaf(n1, cc, a1[d]);
                    a2[d] = fmaf(n2, cc, a2[d]);
                    a3[d] = fmaf(n3, cc, a3[d]);
                }
            }
        }
        __syncthreads();   // done reading q-basis; sbuf about to be overwritten

        // ---- A2: stage t-basis chunk (3 arrays), global stride 20 -> LDS stride 21 ----
        {
            const float* s0 = Ntb   + (size_t)c * CHK * KT;
            const float* s1 = dNtb  + (size_t)c * CHK * KT;
            const float* s2 = ddNtb + (size_t)c * CHK * KT;
            #pragma unroll 1
            for (int j = 0; j < KT; ++j) {
                const unsigned g = (unsigned)(j * 256 + tid);   // < 5120, coalesced
                const unsigned t = g / 20u;
                const unsigned k = g - t * 20u;
                const unsigned l = t * KTP + k;
                sbuf[0 * TB_STR + l] = s0[g];
                sbuf[1 * TB_STR + l] = s1[g];
                sbuf[2 * TB_STR + l] = s2[g];
            }
        }
        __syncthreads();

        // ---- B2: time-spline sums from LDS (stride 21, conflict-free) ----
        float dtau = 0.f, ddtau = 0.f, dddtau = 0.f;
        {
            const float* p = sbuf + tid * KTP;
            #pragma unroll
            for (int k = 0; k < KT; ++k) {
                const float tc = tcp[k];
                dtau   = fmaf(p[k],              tc, dtau);
                ddtau  = fmaf(p[1 * TB_STR + k], tc, ddtau);
                dddtau = fmaf(p[2 * TB_STR + k], tc, dddtau);
            }
        }
        const float dtau2 = dtau * dtau;
        const float dtau3 = dtau2 * dtau;
        const float dtv   = 1.0f / (dtau * (float)TT);
        out[OFF_DT + (size_t)b * TT + c * CHK + tid] = dtv;   // coalesced
        __syncthreads();   // done reading t-basis

        // ---- finalize + stage outputs in global layout (stride 7, conflict-free) ----
        #pragma unroll
        for (int d = 0; d < NDOF; ++d) {
            const float qd   = a1[d] * dtau;
            const float qdd  = a2[d] * dtau2 + ddtau * a1[d] * dtau;
            const float qddd = a3[d] * dtau3 + 3.0f * a2[d] * ddtau * dtau2
                             + a1[d] * dtau2 * dddtau + a1[d] * ddtau * ddtau * dtau;
            const int o = tid * NDOF + d;
            sbuf[0 * OS_STR + o] = aq[d];
            sbuf[1 * OS_STR + o] = qd;
            sbuf[2 * OS_STR + o] = qdd;
            sbuf[3 * OS_STR + o] = qddd;
            lqd[d]   += hub(qd,   qd_lim[d])   * dtv;
            lqdd[d]  += hub(qdd,  qdd_lim[d])  * dtv;
            lqddd[d] += hub(qddd, qddd_lim[d]) * dtv;
        }
        __syncthreads();

        // ---- copy-out: fully coalesced dword stores (+ torque zeros inline) ----
        {
            const size_t gb = (size_t)b * TT * NDOF + (size_t)c * OS_STR;
            #pragma unroll
            for (int j = 0; j < NDOF; ++j) {
                const int f = j * 256 + tid;
                out[OFF_Q    + gb + f] = sbuf[0 * OS_STR + f];
                out[OFF_QD   + gb + f] = sbuf[1 * OS_STR + f];
                out[OFF_QDD  + gb + f] = sbuf[2 * OS_STR + f];
                out[OFF_QDDD + gb + f] = sbuf[3 * OS_STR + f];
                out[OFF_TQ   + gb + f] = 0.0f;
            }
        }
        __syncthreads();   // sbuf free for next chunk
    }

    // ---- block-wide inclusive scan of dt for t_cumsum / t ----
    // dt readback from global (block-local data, visible after __syncthreads)
    const int s4 = 4 * tid;
    const size_t dtb = OFF_DT + (size_t)b * TT;
    const float d0 = out[dtb + s4 + 0];
    const float d1 = out[dtb + s4 + 1];
    const float d2 = out[dtb + s4 + 2];
    const float d3 = out[dtb + s4 + 3];
    const float c0 = d0;
    const float c1 = c0 + d1;
    const float c2 = c1 + d2;
    const float c3 = c2 + d3;

    float* seg  = sbuf + 1024;   // [256]
    float* wred = sbuf + 1280;   // [84]
    seg[tid] = c3;
    __syncthreads();
    #pragma unroll
    for (int off = 1; off < 256; off <<= 1) {
        float v = 0.0f;
        if (tid >= off) v = seg[tid - off];
        __syncthreads();
        if (tid >= off) seg[tid] += v;
        __syncthreads();
    }
    const float excl  = (tid > 0) ? seg[tid - 1] : 0.0f;
    const float total = seg[255];

    // stage t_cumsum in sbuf[0..1024) then coalesced copy-out
    sbuf[s4 + 0] = c0 + excl;
    sbuf[s4 + 1] = c1 + excl;
    sbuf[s4 + 2] = c2 + excl;
    sbuf[s4 + 3] = c3 + excl;
    __syncthreads();
    {
        const size_t tb = OFF_TCUM + (size_t)b * TT;
        #pragma unroll
        for (int j = 0; j < 4; ++j) {
            const int f = j * 256 + tid;
            out[tb + f] = sbuf[f];
        }
    }
    if (tid == 0) out[OFF_T + b] = total;
    if (tid < NDOF) out[OFF_TQL + (size_t)b * NDOF + tid] = 0.0f;  // torque == 0

    // ---- loss reduction: wave shuffle -> LDS -> block ----
    const int lane = tid & 63;
    const int wv   = tid >> 6;
    #pragma unroll
    for (int d = 0; d < NDOF; d++) {
        float v0 = lqd[d], v1 = lqdd[d], v2 = lqddd[d];
        #pragma unroll
        for (int off = 32; off > 0; off >>= 1) {
            v0 += __shfl_down(v0, off);
            v1 += __shfl_down(v1, off);
            v2 += __shfl_down(v2, off);
        }
        if (lane == 0) {
            wred[wv * 21 + d]          = v0;
            wred[wv * 21 + NDOF + d]   = v1;
            wred[wv * 21 + 2*NDOF + d] = v2;
        }
    }
    __syncthreads();
    if (tid < 21) {
        float s = wred[tid] + wred[21 + tid] + wred[42 + tid] + wred[63 + tid];
        const int d     = tid % NDOF;
        const int which = tid / NDOF;
        const size_t o = (which == 0) ? (size_t)OFF_QDL : (which == 1) ? (size_t)OFF_QDDL : (size_t)OFF_QDDDL;
        out[o + (size_t)b * NDOF + d] = s;
        wred[tid] = s;   // stash block partial for model_loss
    }
    __syncthreads();
    if (tid == 0) {
        float p = 0.f;
        #pragma unroll
        for (int j = 0; j < 21; j++) p += wred[j];
        atomicAdd(out + OFF_MODEL, p);
    }
}

extern "C" void kernel_launch(void* const* d_in, const int* in_sizes, int n_in,
                              void* d_out, int out_size, void* d_ws, size_t ws_size,
                              hipStream_t stream) {
    const float* q_cps    = (const float*)d_in[0];
    const float* t_cps    = (const float*)d_in[1];
    const float* Nb       = (const float*)d_in[2];
    const float* dNb      = (const float*)d_in[3];
    const float* ddNb     = (const float*)d_in[4];
    const float* dddNb    = (const float*)d_in[5];
    const float* Ntb      = (const float*)d_in[6];
    const float* dNtb     = (const float*)d_in[7];
    const float* ddNtb    = (const float*)d_in[8];
    const float* qd_lim   = (const float*)d_in[9];
    const float* qdd_lim  = (const float*)d_in[10];
    const float* qddd_lim = (const float*)d_in[11];
    // d_in[12] = torque_limits — unused (torque is identically zero)
    float* out = (float*)d_out;

    // model_loss is accumulated with atomicAdd — zero it first (capturable).
    hipMemsetAsync(d_out, 0, sizeof(float), stream);
    feas_main<<<dim3(BB), dim3(256), 0, stream>>>(
        q_cps, t_cps, Nb, dNb, ddNb, dddNb, Ntb, dNtb, ddNtb,
        qd_lim, qdd_lim, qddd_lim, out);
}

// Round 3
// 230.273 us; speedup vs baseline: 1.2294x; 1.2294x over previous
//
#include <hip/hip_runtime.h>

#define BB 1024
#define TT 1024
#define KQ 15
#define KT 20
#define KTP 21               // padded t-basis LDS stride (odd -> conflict-free)
#define NDOF 7
#define TTILE 64             // t's per block (one per lane)
#define NTTILE (TT/TTILE)    // 16
#define BW 4                 // b's per block (one per wave)
#define NBGRP (BB/BW)        // 256

// Output layout (flat float offsets, in reference return order)
#define OFF_MODEL 0
#define OFF_QDL   1
#define OFF_QDDL  (1 + BB*NDOF)
#define OFF_QDDDL (1 + 2*BB*NDOF)
#define OFF_TQL   (1 + 3*BB*NDOF)
#define OFF_Q     (1 + 4*BB*NDOF)
#define OFF_QD    (OFF_Q    + (size_t)BB*TT*NDOF)
#define OFF_QDD   (OFF_QD   + (size_t)BB*TT*NDOF)
#define OFF_QDDD  (OFF_QDD  + (size_t)BB*TT*NDOF)
#define OFF_TQ    (OFF_QDDD + (size_t)BB*TT*NDOF)
#define OFF_T     (OFF_TQ   + (size_t)BB*TT*NDOF)
#define OFF_TCUM  (OFF_T    + (size_t)BB)
#define OFF_DT    (OFF_TCUM + (size_t)BB*TT)

__device__ __forceinline__ float hub(float v, float lim) {
    // huber(relu(|v| - lim)), delta = 1.0
    float x = fabsf(v) - lim;
    x = fmaxf(x, 0.0f);
    return (x < 1.0f) ? 0.5f * x * x : (x - 0.5f);
}

// 16B store at a possibly 4B-aligned address (gfx950 supports unaligned global);
// memcpy keeps it correct even if the compiler decides to split.
__device__ __forceinline__ void st4(float* p, float x0, float x1, float x2, float x3) {
    float v[4] = {x0, x1, x2, x3};
    __builtin_memcpy(p, v, 16);
}

__global__ __launch_bounds__(256, 4) void feas_main(
    const float* __restrict__ q_cps, const float* __restrict__ t_cps,
    const float* __restrict__ Nb,  const float* __restrict__ dNb,
    const float* __restrict__ ddNb, const float* __restrict__ dddNb,
    const float* __restrict__ Ntb, const float* __restrict__ dNtb,
    const float* __restrict__ ddNtb,
    const float* __restrict__ qd_lim, const float* __restrict__ qdd_lim,
    const float* __restrict__ qddd_lim,
    float* __restrict__ out)
{
    const int ttile = blockIdx.x;       // which 64-t tile
    const int bgrp  = blockIdx.y;       // which group of 4 b's
    const int tid   = threadIdx.x;
    const int lane  = tid & 63;
    const int w     = tid >> 6;
    // wave-uniform batch index -> scalar loads for cps/tcp
    const int bw = __builtin_amdgcn_readfirstlane(bgrp * BW + w);

    __shared__ __align__(16) float qb[4 * TTILE * KQ];   // 3840 fl: 4 q-basis tiles, stride 15
    __shared__ float tb[3 * TTILE * KTP];                // 4032 fl: 3 t-basis tiles, stride 21
    __shared__ float lred[BW * 21];                      // per-wave loss partials

    // ---- stage basis tiles ONCE per block (shared by all 4 waves/b's) ----
    // q-basis: 4 arrays x 960 contiguous dwords each -> float4 coalesced
    {
        const size_t gq = (size_t)ttile * TTILE * KQ;
        if (tid < 240) {
            const float4 v0 = *(const float4*)(Nb    + gq + tid * 4);
            const float4 v1 = *(const float4*)(dNb   + gq + tid * 4);
            const float4 v2 = *(const float4*)(ddNb  + gq + tid * 4);
            const float4 v3 = *(const float4*)(dddNb + gq + tid * 4);
            *(float4*)(qb + 0 * TTILE * KQ + tid * 4) = v0;
            *(float4*)(qb + 1 * TTILE * KQ + tid * 4) = v1;
            *(float4*)(qb + 2 * TTILE * KQ + tid * 4) = v2;
            *(float4*)(qb + 3 * TTILE * KQ + tid * 4) = v3;
        }
        // t-basis: 3 arrays x 1280 dwords, repack stride 20 -> 21
        const size_t gt = (size_t)ttile * TTILE * KT;
        #pragma unroll
        for (int j = 0; j < 5; ++j) {
            const unsigned g = (unsigned)(j * 256 + tid);   // < 1280 exactly
            const unsigned t = g / 20u;
            const unsigned k = g - t * 20u;
            const unsigned l = t * KTP + k;
            tb[0 * TTILE * KTP + l] = Ntb [gt + g];
            tb[1 * TTILE * KTP + l] = dNtb[gt + g];
            tb[2 * TTILE * KTP + l] = ddNtb[gt + g];
        }
    }
    __syncthreads();

    // ---- per-wave compute: wave handles batch bw, lane handles t = ttile*64+lane ----
    const float* cps = q_cps + (size_t)bw * KQ * NDOF;   // uniform -> s_load
    const float* tcp = t_cps + (size_t)bw * KT;          // uniform -> s_load

    // time-spline sums (LDS stride 21, conflict-free)
    float dtau = 0.f, ddtau = 0.f, dddtau = 0.f;
    {
        const float* p = tb + lane * KTP;
        #pragma unroll
        for (int k = 0; k < KT; ++k) {
            const float tc = tcp[k];
            dtau   = fmaf(p[k],                  tc, dtau);
            ddtau  = fmaf(p[1 * TTILE * KTP + k], tc, ddtau);
            dddtau = fmaf(p[2 * TTILE * KTP + k], tc, dddtau);
        }
    }

    // q-spline sums (LDS stride 15, conflict-free)
    float aq[NDOF], a1[NDOF], a2[NDOF], a3[NDOF];
    #pragma unroll
    for (int d = 0; d < NDOF; ++d) { aq[d] = 0.f; a1[d] = 0.f; a2[d] = 0.f; a3[d] = 0.f; }
    {
        const float* p = qb + lane * KQ;
        #pragma unroll
        for (int k = 0; k < KQ; ++k) {
            const float n0 = p[k];
            const float n1 = p[1 * TTILE * KQ + k];
            const float n2 = p[2 * TTILE * KQ + k];
            const float n3 = p[3 * TTILE * KQ + k];
            #pragma unroll
            for (int d = 0; d < NDOF; ++d) {
                const float cc = cps[k * NDOF + d];
                aq[d] = fmaf(n0, cc, aq[d]);
                a1[d] = fmaf(n1, cc, a1[d]);
                a2[d] = fmaf(n2, cc, a2[d]);
                a3[d] = fmaf(n3, cc, a3[d]);
            }
        }
    }

    const float dtau2 = dtau * dtau;
    const float dtau3 = dtau2 * dtau;
    const float dtv   = 1.0f / (dtau * (float)TT);

    float qd[NDOF], qdd[NDOF], qddd[NDOF];
    #pragma unroll
    for (int d = 0; d < NDOF; ++d) {
        qd[d]   = a1[d] * dtau;
        qdd[d]  = a2[d] * dtau2 + ddtau * a1[d] * dtau;
        qddd[d] = a3[d] * dtau3 + 3.0f * a2[d] * ddtau * dtau2
                + a1[d] * dtau2 * dddtau + a1[d] * ddtau * ddtau * dtau;
    }

    // ---- stores: per-lane 7-float rows tile contiguously across the wave ----
    {
        const size_t ob = (size_t)bw * (TT * NDOF) + (size_t)(ttile * TTILE + lane) * NDOF;
        st4(out + OFF_Q    + ob,     aq[0],   aq[1],   aq[2],   aq[3]);
        st4(out + OFF_Q    + ob + 3, aq[3],   aq[4],   aq[5],   aq[6]);
        st4(out + OFF_QD   + ob,     qd[0],   qd[1],   qd[2],   qd[3]);
        st4(out + OFF_QD   + ob + 3, qd[3],   qd[4],   qd[5],   qd[6]);
        st4(out + OFF_QDD  + ob,     qdd[0],  qdd[1],  qdd[2],  qdd[3]);
        st4(out + OFF_QDD  + ob + 3, qdd[3],  qdd[4],  qdd[5],  qdd[6]);
        st4(out + OFF_QDDD + ob,     qddd[0], qddd[1], qddd[2], qddd[3]);
        st4(out + OFF_QDDD + ob + 3, qddd[3], qddd[4], qddd[5], qddd[6]);
        st4(out + OFF_TQ   + ob,     0.f, 0.f, 0.f, 0.f);   // torque == 0
        st4(out + OFF_TQ   + ob + 3, 0.f, 0.f, 0.f, 0.f);
        out[OFF_DT + (size_t)bw * TT + ttile * TTILE + lane] = dtv;   // coalesced
    }

    // ---- losses: 21 values per lane, wave shuffle-reduce over the 64 t's ----
    float ls[21];
    #pragma unroll
    for (int d = 0; d < NDOF; ++d) {
        ls[d]          = hub(qd[d],   qd_lim[d])   * dtv;
        ls[NDOF + d]   = hub(qdd[d],  qdd_lim[d])  * dtv;
        ls[2*NDOF + d] = hub(qddd[d], qddd_lim[d]) * dtv;
    }
    #pragma unroll
    for (int j = 0; j < 21; ++j) {
        float v = ls[j];
        #pragma unroll
        for (int off = 32; off > 0; off >>= 1) v += __shfl_down(v, off);
        ls[j] = v;   // valid at lane 0
    }
    if (lane == 0) {
        #pragma unroll
        for (int j = 0; j < 21; ++j) lred[w * 21 + j] = ls[j];
    }
    __syncthreads();
    if (tid < BW * 21) {
        const int wv = tid / 21, j = tid - wv * 21;
        const int which = j / NDOF, d = j - which * NDOF;
        const size_t o = (which == 0) ? (size_t)OFF_QDL
                       : (which == 1) ? (size_t)OFF_QDDL : (size_t)OFF_QDDDL;
        atomicAdd(out + o + (size_t)(bgrp * BW + wv) * NDOF + d, lred[tid]);
    }
    if (tid == 0) {
        float s = 0.f;
        #pragma unroll
        for (int j = 0; j < BW * 21; ++j) s += lred[j];
        atomicAdd(out + OFF_MODEL, s);
    }
}

// one block per b: inclusive scan of dt -> t_cumsum, total -> t  (R2-verified logic)
__global__ __launch_bounds__(256) void feas_scan(float* __restrict__ out)
{
    __shared__ float sb[TT];
    __shared__ float seg[256];
    const int b   = blockIdx.x;
    const int tid = threadIdx.x;

    const int s4 = 4 * tid;
    const size_t dtb = OFF_DT + (size_t)b * TT;
    const float d0 = out[dtb + s4 + 0];
    const float d1 = out[dtb + s4 + 1];
    const float d2 = out[dtb + s4 + 2];
    const float d3 = out[dtb + s4 + 3];
    const float c0 = d0;
    const float c1 = c0 + d1;
    const float c2 = c1 + d2;
    const float c3 = c2 + d3;

    seg[tid] = c3;
    __syncthreads();
    #pragma unroll
    for (int off = 1; off < 256; off <<= 1) {
        float v = 0.0f;
        if (tid >= off) v = seg[tid - off];
        __syncthreads();
        if (tid >= off) seg[tid] += v;
        __syncthreads();
    }
    const float excl  = (tid > 0) ? seg[tid - 1] : 0.0f;
    const float total = seg[255];

    sb[s4 + 0] = c0 + excl;
    sb[s4 + 1] = c1 + excl;
    sb[s4 + 2] = c2 + excl;
    sb[s4 + 3] = c3 + excl;
    __syncthreads();
    const size_t tb = OFF_TCUM + (size_t)b * TT;
    #pragma unroll
    for (int j = 0; j < 4; ++j) {
        const int f = j * 256 + tid;
        out[tb + f] = sb[f];
    }
    if (tid == 0) out[OFF_T + b] = total;
}

extern "C" void kernel_launch(void* const* d_in, const int* in_sizes, int n_in,
                              void* d_out, int out_size, void* d_ws, size_t ws_size,
                              hipStream_t stream) {
    const float* q_cps    = (const float*)d_in[0];
    const float* t_cps    = (const float*)d_in[1];
    const float* Nb       = (const float*)d_in[2];
    const float* dNb      = (const float*)d_in[3];
    const float* ddNb     = (const float*)d_in[4];
    const float* dddNb    = (const float*)d_in[5];
    const float* Ntb      = (const float*)d_in[6];
    const float* dNtb     = (const float*)d_in[7];
    const float* ddNtb    = (const float*)d_in[8];
    const float* qd_lim   = (const float*)d_in[9];
    const float* qdd_lim  = (const float*)d_in[10];
    const float* qddd_lim = (const float*)d_in[11];
    // d_in[12] = torque_limits — unused (torque is identically zero)
    float* out = (float*)d_out;

    // zero the atomic-accumulated loss region [model_loss, q_dot/qdd/qddd losses, torque_loss]
    hipMemsetAsync(d_out, 0, (size_t)OFF_Q * sizeof(float), stream);
    feas_main<<<dim3(NTTILE, NBGRP), dim3(256), 0, stream>>>(
        q_cps, t_cps, Nb, dNb, ddNb, dddNb, Ntb, dNtb, ddNtb,
        qd_lim, qdd_lim, qddd_lim, out);
    feas_scan<<<dim3(BB), dim3(256), 0, stream>>>(out);
}

// Round 4
// 225.719 us; speedup vs baseline: 1.2542x; 1.0202x over previous
//
#include <hip/hip_runtime.h>

#define BB 1024
#define TT 1024
#define KQ 15
#define KT 20
#define KTP 21               // padded t-basis LDS stride (odd -> conflict-free)
#define NDOF 7
#define TTILE 64             // t's per block (one per lane)
#define NTTILE (TT/TTILE)    // 16
#define BW 4                 // b's per block (one per wave)
#define NBGRP (BB/BW)        // 256

// Output layout (flat float offsets, in reference return order)
#define OFF_MODEL 0
#define OFF_QDL   1
#define OFF_QDDL  (1 + BB*NDOF)
#define OFF_QDDDL (1 + 2*BB*NDOF)
#define OFF_TQL   (1 + 3*BB*NDOF)
#define OFF_Q     (1 + 4*BB*NDOF)
#define OFF_QD    (OFF_Q    + (size_t)BB*TT*NDOF)
#define OFF_QDD   (OFF_QD   + (size_t)BB*TT*NDOF)
#define OFF_QDDD  (OFF_QDD  + (size_t)BB*TT*NDOF)
#define OFF_TQ    (OFF_QDDD + (size_t)BB*TT*NDOF)
#define OFF_T     (OFF_TQ   + (size_t)BB*TT*NDOF)
#define OFF_TCUM  (OFF_T    + (size_t)BB)
#define OFF_DT    (OFF_TCUM + (size_t)BB*TT)

// workspace layout (floats): per-(b,ttile) 21 loss partials, then per-b model partial
#define WS_LOSS   0
#define WS_BSUM   ((size_t)BB * NTTILE * 21)

__device__ __forceinline__ float hub(float v, float lim) {
    // huber(relu(|v| - lim)), delta = 1.0
    float x = fabsf(v) - lim;
    x = fmaxf(x, 0.0f);
    return (x < 1.0f) ? 0.5f * x * x : (x - 0.5f);
}

// 16B store at a 4B-aligned address (gfx950 global stores need only dword align)
__device__ __forceinline__ void st4(float* p, float x0, float x1, float x2, float x3) {
    float v[4] = {x0, x1, x2, x3};
    __builtin_memcpy(p, v, 16);
}

__global__ __launch_bounds__(256, 2) void feas_main(
    const float* __restrict__ q_cps, const float* __restrict__ t_cps,
    const float* __restrict__ Nb,  const float* __restrict__ dNb,
    const float* __restrict__ ddNb, const float* __restrict__ dddNb,
    const float* __restrict__ Ntb, const float* __restrict__ dNtb,
    const float* __restrict__ ddNtb,
    const float* __restrict__ qd_lim, const float* __restrict__ qdd_lim,
    const float* __restrict__ qddd_lim,
    float* __restrict__ out, float* __restrict__ lws)
{
    const int ttile = blockIdx.x;       // which 64-t tile
    const int bgrp  = blockIdx.y;       // which group of 4 b's
    const int tid   = threadIdx.x;
    const int lane  = tid & 63;
    const int w     = tid >> 6;
    // wave-uniform batch index -> scalar loads for cps/tcp
    const int bw = __builtin_amdgcn_readfirstlane(bgrp * BW + w);

    // phase A: [0..3840) = 4 q-basis tiles (stride 15); [3840..7872) = 3 t-basis tiles (stride 21)
    // phase B: [0..7168) = 16 regions of 448 floats: (wave w, array a) at (w*4+a)*448
    __shared__ __align__(16) float smem[3840 + 3 * TTILE * KTP];
    float* qb = smem;
    float* tb = smem + 3840;

    // ---- stage basis tiles ONCE per block (shared by all 4 waves/b's) ----
    {
        const size_t gq = (size_t)ttile * (TTILE * KQ);
        if (tid < 240) {
            const float4 v0 = *(const float4*)(Nb    + gq + tid * 4);
            const float4 v1 = *(const float4*)(dNb   + gq + tid * 4);
            const float4 v2 = *(const float4*)(ddNb  + gq + tid * 4);
            const float4 v3 = *(const float4*)(dddNb + gq + tid * 4);
            *(float4*)(qb + 0 * TTILE * KQ + tid * 4) = v0;
            *(float4*)(qb + 1 * TTILE * KQ + tid * 4) = v1;
            *(float4*)(qb + 2 * TTILE * KQ + tid * 4) = v2;
            *(float4*)(qb + 3 * TTILE * KQ + tid * 4) = v3;
        }
        const size_t gt = (size_t)ttile * (TTILE * KT);
        #pragma unroll
        for (int j = 0; j < 5; ++j) {
            const unsigned g = (unsigned)(j * 256 + tid);   // < 1280 exactly
            const unsigned t = g / 20u;
            const unsigned k = g - t * 20u;
            const unsigned l = t * KTP + k;
            tb[0 * TTILE * KTP + l] = Ntb [gt + g];
            tb[1 * TTILE * KTP + l] = dNtb[gt + g];
            tb[2 * TTILE * KTP + l] = ddNtb[gt + g];
        }
    }
    __syncthreads();

    // ---- per-wave compute: wave handles batch bw, lane handles t = ttile*64+lane ----
    const float* cps = q_cps + (size_t)bw * KQ * NDOF;   // uniform -> s_load
    const float* tcp = t_cps + (size_t)bw * KT;          // uniform -> s_load

    float dtau = 0.f, ddtau = 0.f, dddtau = 0.f;
    {
        const float* p = tb + lane * KTP;
        #pragma unroll
        for (int k = 0; k < KT; ++k) {
            const float tc = tcp[k];
            dtau   = fmaf(p[k],                   tc, dtau);
            ddtau  = fmaf(p[1 * TTILE * KTP + k], tc, ddtau);
            dddtau = fmaf(p[2 * TTILE * KTP + k], tc, dddtau);
        }
    }

    float aq[NDOF], a1[NDOF], a2[NDOF], a3[NDOF];
    #pragma unroll
    for (int d = 0; d < NDOF; ++d) { aq[d] = 0.f; a1[d] = 0.f; a2[d] = 0.f; a3[d] = 0.f; }
    {
        const float* p = qb + lane * KQ;
        #pragma unroll
        for (int k = 0; k < KQ; ++k) {
            const float n0 = p[k];
            const float n1 = p[1 * TTILE * KQ + k];
            const float n2 = p[2 * TTILE * KQ + k];
            const float n3 = p[3 * TTILE * KQ + k];
            #pragma unroll
            for (int d = 0; d < NDOF; ++d) {
                const float cc = cps[k * NDOF + d];
                aq[d] = fmaf(n0, cc, aq[d]);
                a1[d] = fmaf(n1, cc, a1[d]);
                a2[d] = fmaf(n2, cc, a2[d]);
                a3[d] = fmaf(n3, cc, a3[d]);
            }
        }
    }

    const float dtau2 = dtau * dtau;
    const float dtau3 = dtau2 * dtau;
    const float dtv   = 1.0f / (dtau * (float)TT);

    float qd[NDOF], qdd[NDOF], qddd[NDOF];
    #pragma unroll
    for (int d = 0; d < NDOF; ++d) {
        qd[d]   = a1[d] * dtau;
        qdd[d]  = a2[d] * dtau2 + ddtau * a1[d] * dtau;
        qddd[d] = a3[d] * dtau3 + 3.0f * a2[d] * ddtau * dtau2
                + a1[d] * dtau2 * dddtau + a1[d] * ddtau * ddtau * dtau;
    }

    out[OFF_DT + (size_t)bw * TT + ttile * TTILE + lane] = dtv;   // coalesced

    // ---- losses: 21 values per lane, wave shuffle-reduce, plain store to ws ----
    {
        float ls[21];
        #pragma unroll
        for (int d = 0; d < NDOF; ++d) {
            ls[d]          = hub(qd[d],   qd_lim[d])   * dtv;
            ls[NDOF + d]   = hub(qdd[d],  qdd_lim[d])  * dtv;
            ls[2*NDOF + d] = hub(qddd[d], qddd_lim[d]) * dtv;
        }
        #pragma unroll
        for (int j = 0; j < 21; ++j) {
            float v = ls[j];
            #pragma unroll
            for (int off = 32; off > 0; off >>= 1) v += __shfl_down(v, off);
            ls[j] = v;   // valid at lane 0
        }
        if (lane == 0) {
            float* wp = lws + WS_LOSS + ((size_t)bw * NTTILE + ttile) * 21;
            #pragma unroll
            for (int j = 0; j < 21; ++j) wp[j] = ls[j];
        }
    }

    // ---- copy-out via LDS transpose -> aligned contiguous dwordx4 runs ----
    __syncthreads();   // all waves done reading qb/tb
    {
        // stage: region (w,arr) = smem + (w*4+arr)*448; write stride 7 (odd -> conflict-free)
        float* r = smem + (size_t)(w * 4) * (TTILE * NDOF) + lane * NDOF;
        #pragma unroll
        for (int d = 0; d < NDOF; ++d) {
            r[0 * TTILE * NDOF + d] = aq[d];
            r[1 * TTILE * NDOF + d] = qd[d];
            r[2 * TTILE * NDOF + d] = qdd[d];
            r[3 * TTILE * NDOF + d] = qddd[d];
        }
    }
    __syncthreads();
    {
        const size_t gb = (size_t)bw * (TT * NDOF) + (size_t)ttile * (TTILE * NDOF);
        const float* rb = smem + (size_t)(w * 4) * (TTILE * NDOF);
        #pragma unroll
        for (int a = 0; a < 4; ++a) {
            const size_t off = (a == 0) ? (size_t)OFF_Q : (a == 1) ? (size_t)OFF_QD
                             : (a == 2) ? (size_t)OFF_QDD : (size_t)OFF_QDDD;
            const float* s = rb + a * (TTILE * NDOF);
            const float4 x0 = *(const float4*)(s + lane * 4);
            st4(out + off + gb + lane * 4, x0.x, x0.y, x0.z, x0.w);
            if (lane < 48) {
                const float4 x1 = *(const float4*)(s + 256 + lane * 4);
                st4(out + off + gb + 256 + lane * 4, x1.x, x1.y, x1.z, x1.w);
            }
        }
        st4(out + OFF_TQ + gb + lane * 4, 0.f, 0.f, 0.f, 0.f);   // torque == 0
        if (lane < 48) st4(out + OFF_TQ + gb + 256 + lane * 4, 0.f, 0.f, 0.f, 0.f);
    }
}

// one block per b: inclusive scan of dt -> t_cumsum/t, plus loss finalize from ws
__global__ __launch_bounds__(256) void feas_scan(
    float* __restrict__ out, const float* __restrict__ lws, float* __restrict__ bsum)
{
    __shared__ float sb[TT];
    __shared__ float seg[256];
    __shared__ float lsum[21];
    const int b   = blockIdx.x;
    const int tid = threadIdx.x;

    const int s4 = 4 * tid;
    const size_t dtb = OFF_DT + (size_t)b * TT;
    const float d0 = out[dtb + s4 + 0];
    const float d1 = out[dtb + s4 + 1];
    const float d2 = out[dtb + s4 + 2];
    const float d3 = out[dtb + s4 + 3];
    const float c0 = d0;
    const float c1 = c0 + d1;
    const float c2 = c1 + d2;
    const float c3 = c2 + d3;

    seg[tid] = c3;
    __syncthreads();
    #pragma unroll
    for (int off = 1; off < 256; off <<= 1) {
        float v = 0.0f;
        if (tid >= off) v = seg[tid - off];
        __syncthreads();
        if (tid >= off) seg[tid] += v;
        __syncthreads();
    }
    const float excl  = (tid > 0) ? seg[tid - 1] : 0.0f;
    const float total = seg[255];

    sb[s4 + 0] = c0 + excl;
    sb[s4 + 1] = c1 + excl;
    sb[s4 + 2] = c2 + excl;
    sb[s4 + 3] = c3 + excl;

    // loss finalize: reduce 16 ttile partials per (b, j)
    if (tid < 21) {
        const float* wp = lws + WS_LOSS + (size_t)b * NTTILE * 21 + tid;
        float s = 0.f;
        #pragma unroll
        for (int tt = 0; tt < NTTILE; ++tt) s += wp[tt * 21];
        const int which = tid / NDOF, d = tid - which * NDOF;
        const size_t o = (which == 0) ? (size_t)OFF_QDL
                       : (which == 1) ? (size_t)OFF_QDDL : (size_t)OFF_QDDDL;
        out[o + (size_t)b * NDOF + d] = s;
        lsum[tid] = s;
    }
    if (tid < NDOF) out[OFF_TQL + (size_t)b * NDOF + tid] = 0.0f;  // torque == 0
    __syncthreads();

    const size_t tb = OFF_TCUM + (size_t)b * TT;
    #pragma unroll
    for (int j = 0; j < 4; ++j) {
        const int f = j * 256 + tid;
        out[tb + f] = sb[f];
    }
    if (tid == 0) {
        out[OFF_T + b] = total;
        float p = 0.f;
        #pragma unroll
        for (int j = 0; j < 21; ++j) p += lsum[j];
        bsum[b] = p;   // per-b model partial (no atomics)
    }
}

// single block: model_loss = sum of 1024 per-b partials
__global__ __launch_bounds__(256) void feas_final(
    const float* __restrict__ bsum, float* __restrict__ out)
{
    __shared__ float wsums[4];
    const int tid  = threadIdx.x;
    const int lane = tid & 63;
    const int w    = tid >> 6;
    float v = 0.f;
    #pragma unroll
    for (int j = 0; j < 4; ++j) v += bsum[j * 256 + tid];
    #pragma unroll
    for (int off = 32; off > 0; off >>= 1) v += __shfl_down(v, off);
    if (lane == 0) wsums[w] = v;
    __syncthreads();
    if (tid == 0) out[OFF_MODEL] = wsums[0] + wsums[1] + wsums[2] + wsums[3];
}

extern "C" void kernel_launch(void* const* d_in, const int* in_sizes, int n_in,
                              void* d_out, int out_size, void* d_ws, size_t ws_size,
                              hipStream_t stream) {
    const float* q_cps    = (const float*)d_in[0];
    const float* t_cps    = (const float*)d_in[1];
    const float* Nb       = (const float*)d_in[2];
    const float* dNb      = (const float*)d_in[3];
    const float* ddNb     = (const float*)d_in[4];
    const float* dddNb    = (const float*)d_in[5];
    const float* Ntb      = (const float*)d_in[6];
    const float* dNtb     = (const float*)d_in[7];
    const float* ddNtb    = (const float*)d_in[8];
    const float* qd_lim   = (const float*)d_in[9];
    const float* qdd_lim  = (const float*)d_in[10];
    const float* qddd_lim = (const float*)d_in[11];
    // d_in[12] = torque_limits — unused (torque is identically zero)
    float* out = (float*)d_out;
    float* lws = (float*)d_ws;               // 1024*16*21 + 1024 floats ≈ 1.4 MB

    feas_main<<<dim3(NTTILE, NBGRP), dim3(256), 0, stream>>>(
        q_cps, t_cps, Nb, dNb, ddNb, dddNb, Ntb, dNtb, ddNtb,
        qd_lim, qdd_lim, qddd_lim, out, lws);
    feas_scan<<<dim3(BB), dim3(256), 0, stream>>>(out, lws, lws + WS_BSUM);
    feas_final<<<dim3(1), dim3(256), 0, stream>>>(lws + WS_BSUM, out);
}